// Round 7
// baseline (911.994 us; speedup 1.0000x reference)
//
#include <hip/hip_runtime.h>
#include <math.h>

#define N_NODES 100000
#define N_EDGES 1600000
#define LN_EPS 1e-5f
#define NBUK 782          // ceil(100000/128) buckets of 128 nodes
#define BCAP 2560         // bucket capacity (mean 2046, sd ~45; ~11 sigma)
#define BIN_TILE 4096     // edges per k_bin block

using bf16x8 = __attribute__((ext_vector_type(8))) short;
using f32x4  = __attribute__((ext_vector_type(4))) float;

__device__ __forceinline__ unsigned short f2bf(float f) {
    unsigned u = __float_as_uint(f);
    u += 0x7fffu + ((u >> 16) & 1u);            // round-to-nearest-even
    return (unsigned short)(u >> 16);
}
__device__ __forceinline__ float bflo(unsigned u) { return __uint_as_float(u << 16); }
__device__ __forceinline__ float bfhi(unsigned u) { return __uint_as_float(u & 0xffff0000u); }
__device__ __forceinline__ unsigned bfpack(float a, float b) {
    return (unsigned)f2bf(a) | ((unsigned)f2bf(b) << 16);
}

// ---------------- converts ----------------

__global__ void k_cvt(const f32x4* __restrict__ x, unsigned* __restrict__ xb) {
    int i = blockIdx.x * 256 + threadIdx.x;     // 4 floats per thread
    if (i < N_NODES * 32) {
        f32x4 v = __builtin_nontemporal_load(&x[i]);
        xb[2 * i]     = bfpack(v[0], v[1]);
        xb[2 * i + 1] = bfpack(v[2], v[3]);
    }
}

// all three weights fp32 -> transposed bf16 in one launch
__global__ void k_wtall(const float* __restrict__ W1, const float* __restrict__ W2,
                        const float* __restrict__ Wm1, short* __restrict__ Wt1,
                        short* __restrict__ Wt2, short* __restrict__ Wm1t) {
    int i = blockIdx.x * 256 + threadIdx.x;
    if (i < 16384) {
        int k = i >> 7, c = i & 127;
        Wt1[c * 128 + k] = (short)f2bf(W1[i]);
    } else if (i < 32768) {
        int j = i - 16384, k = j >> 7, c = j & 127;
        Wt2[c * 128 + k] = (short)f2bf(W2[j]);
    } else if (i < 65536) {
        int j = i - 32768, k = j >> 7, c = j & 127;
        Wm1t[c * 256 + k] = (short)f2bf(Wm1[j]);
    }
}

// ---------------- bucketed CSR build ----------------
__global__ __launch_bounds__(256) void k_bin(
    const int* __restrict__ src, const int* __restrict__ dst,
    int* __restrict__ gcur, unsigned* __restrict__ pairs) {
    __shared__ int bcnt[NBUK];
    __shared__ int bbase[NBUK];
    int t = threadIdx.x;
    for (int i = t; i < NBUK; i += 256) bcnt[i] = 0;
    __syncthreads();
    int e0 = blockIdx.x * BIN_TILE;
    int e1 = e0 + BIN_TILE; if (e1 > N_EDGES) e1 = N_EDGES;
    for (int e = e0 + t; e < e1; e += 256) {
        int d = __builtin_nontemporal_load(&dst[e]);
        atomicAdd(&bcnt[d >> 7], 1);
    }
    __syncthreads();
    for (int i = t; i < NBUK; i += 256) {
        int c = bcnt[i];
        bbase[i] = (c > 0) ? atomicAdd(&gcur[i], c) : 0;
        bcnt[i] = 0;
    }
    __syncthreads();
    for (int e = e0 + t; e < e1; e += 256) {
        int d = __builtin_nontemporal_load(&dst[e]);
        int s = __builtin_nontemporal_load(&src[e]);
        int b = d >> 7;
        int idx = bbase[b] + atomicAdd(&bcnt[b], 1);
        if (idx < BCAP)
            pairs[(size_t)b * BCAP + idx] = ((unsigned)(d & 127) << 25) | (unsigned)s;
    }
}

__global__ void k_bstart(const int* __restrict__ gcur, int* __restrict__ bstart,
                         int* __restrict__ rowptr) {
    __shared__ int s[1024];
    int tid = threadIdx.x;
    int v = (tid < NBUK) ? gcur[tid] : 0;
    s[tid] = v;
    __syncthreads();
    for (int o = 1; o < 1024; o <<= 1) {
        int tv = (tid >= o) ? s[tid - o] : 0;
        __syncthreads();
        s[tid] += tv;
        __syncthreads();
    }
    if (tid < NBUK) bstart[tid] = s[tid] - v;
    if (tid == 0) rowptr[N_NODES] = N_EDGES;
}

__global__ __launch_bounds__(256) void k_csr(
    const unsigned* __restrict__ pairs, const int* __restrict__ gcur,
    const int* __restrict__ bstart, int* __restrict__ rowptr,
    float* __restrict__ dinv, int* __restrict__ col) {
    int b = blockIdx.x;
    int t = threadIdx.x;
    int lo = b << 7;
    int nloc = N_NODES - lo; if (nloc > 128) nloc = 128;
    int size = gcur[b]; if (size > BCAP) size = BCAP;
    int base = bstart[b];
    __shared__ int lcnt[128], lofs[128], lcur[128];
    if (t < 128) lcnt[t] = 0;
    __syncthreads();
    const unsigned* bp = pairs + (size_t)b * BCAP;
    for (int i = t; i < size; i += 256) atomicAdd(&lcnt[bp[i] >> 25], 1);
    __syncthreads();
    if (t < 128) lofs[t] = lcnt[t];
    __syncthreads();
    for (int o = 1; o < 128; o <<= 1) {
        int v = 0;
        if (t < 128 && t >= o) v = lofs[t - o];
        __syncthreads();
        if (t < 128) lofs[t] += v;
        __syncthreads();
    }
    if (t < 128) {
        int ex = lofs[t] - lcnt[t];               // exclusive
        if (t < nloc) {
            rowptr[lo + t] = base + ex;
            dinv[lo + t] = rsqrtf((float)(lcnt[t] + 1));
        }
        lcur[t] = ex;
    }
    __syncthreads();
    for (int i = t; i < size; i += 256) {
        unsigned w = bp[i];
        int pos = atomicAdd(&lcur[w >> 25], 1);
        col[base + pos] = (int)(w & 0x1FFFFFFu);
    }
}

// ------------- bf16 MFMA GEMM  C[N,128] = A[N,K] @ W[K,128] -------------
// MODE 0: epilogue *dinv[row], write bf16 C.
// MODE 1: A=concat(A0,A1) (K=256); epilogue relu(.+bias) @ Wm2 + bm2 -> out[N,2]
template <int MODE, int KSTEPS>
__global__ __launch_bounds__(256) void k_gemm_mfma(
    const short* __restrict__ A0, const short* __restrict__ A1,
    const short* __restrict__ Wt, const float* __restrict__ dinv,
    const float* __restrict__ bias, short* __restrict__ C,
    const float* __restrict__ Wm2, const float* __restrict__ bm2,
    float* __restrict__ out) {
    constexpr int K = KSTEPS * 32;
    int t = threadIdx.x;
    int wave = t >> 6, lane = t & 63;
    int quad = lane >> 4, fr = lane & 15;
    int row0 = blockIdx.x * 64 + wave * 16;
    int arow = row0 + fr;
    if (arow >= N_NODES) arow = N_NODES - 1;

    f32x4 acc[8];
#pragma unroll
    for (int n = 0; n < 8; ++n) acc[n] = (f32x4){0.f, 0.f, 0.f, 0.f};

#pragma unroll
    for (int ks = 0; ks < KSTEPS; ++ks) {
        int kof = ks * 32 + quad * 8;
        const short* Asrc = A0;
        int kk = kof;
        if (MODE == 1 && kof >= 128) { Asrc = A1; kk = kof - 128; }
        bf16x8 a = *(const bf16x8*)(Asrc + (size_t)arow * 128 + kk);
#pragma unroll
        for (int n = 0; n < 8; ++n) {
            bf16x8 b = *(const bf16x8*)(Wt + (size_t)(n * 16 + fr) * K + kof);
            acc[n] = __builtin_amdgcn_mfma_f32_16x16x32_bf16(a, b, acc[n], 0, 0, 0);
        }
    }

    int r0 = row0 + quad * 4;
    if (MODE == 0) {
#pragma unroll
        for (int j = 0; j < 4; ++j) {
            int r = r0 + j;
            if (r < N_NODES) {
                float s = dinv[r];
#pragma unroll
                for (int n = 0; n < 8; ++n)
                    C[(size_t)r * 128 + n * 16 + fr] = (short)f2bf(acc[n][j] * s);
            }
        }
    } else {
        // fused MLP tail: y = relu(acc + bm1); out = y @ Wm2 + bm2
        float pr0[4] = {0.f, 0.f, 0.f, 0.f};
        float pr1[4] = {0.f, 0.f, 0.f, 0.f};
#pragma unroll
        for (int n = 0; n < 8; ++n) {
            int c = n * 16 + fr;
            float bsn = bias[c];
            float2 w = ((const float2*)Wm2)[c];
#pragma unroll
            for (int j = 0; j < 4; ++j) {
                float y = acc[n][j] + bsn;
                y = y > 0.f ? y : 0.f;
                pr0[j] = fmaf(y, w.x, pr0[j]);
                pr1[j] = fmaf(y, w.y, pr1[j]);
            }
        }
#pragma unroll
        for (int o = 1; o < 16; o <<= 1) {
#pragma unroll
            for (int j = 0; j < 4; ++j) {
                pr0[j] += __shfl_xor(pr0[j], o);
                pr1[j] += __shfl_xor(pr1[j], o);
            }
        }
        if (fr == 0) {
            float c0 = bm2[0], c1 = bm2[1];
#pragma unroll
            for (int j = 0; j < 4; ++j) {
                int r = r0 + j;
                if (r < N_NODES) {
                    out[(size_t)r * 2 + 0] = pr0[j] + c0;
                    out[(size_t)r * 2 + 1] = pr1[j] + c1;
                }
            }
        }
    }
}

// ------- channel-sliced pull-aggregate: slice g (8 dwords = 16 ch) on XCD g -------
// hs slice (3.2 MB) stays L2-resident; col/rowptr streamed non-temporally.
// aggS layout [8][N][8] dwords, bf16-pair packed, pre-scaled by dinv[dst].
__global__ __launch_bounds__(256) void k_sagg(
    const unsigned* __restrict__ hs2, const int* __restrict__ rowptr,
    const int* __restrict__ col, const float* __restrict__ dinv,
    unsigned* __restrict__ aggS) {
    int g = blockIdx.x & 7;                      // slice == XCD (round-robin dispatch)
    int nb = blockIdx.x >> 3;
    int wave = threadIdx.x >> 6, lane = threadIdx.x & 63;
    int eg = lane >> 3, ch = lane & 7;
    int chof = g * 8 + ch;
    int wv0 = (nb * 4 + wave) * 8;
#pragma unroll 1
    for (int i = 0; i < 8; ++i) {
        int wv = wv0 + i;
        if (wv >= N_NODES) break;
        int p0 = __builtin_nontemporal_load(&rowptr[wv]);
        int p1 = __builtin_nontemporal_load(&rowptr[wv + 1]);
        int ne = p1 - p0;
        float ax = 0.f, ay = 0.f;
        for (int base = 0; base < ne; base += 16) {
            int e0 = base + eg, e1 = base + 8 + eg;
            int s0 = (e0 < ne) ? __builtin_nontemporal_load(&col[p0 + e0]) : -1;
            int s1 = (e1 < ne) ? __builtin_nontemporal_load(&col[p0 + e1]) : -1;
            unsigned u0 = (s0 >= 0) ? hs2[(size_t)s0 * 64 + chof] : 0u;
            unsigned u1 = (s1 >= 0) ? hs2[(size_t)s1 * 64 + chof] : 0u;
            ax += bflo(u0) + bflo(u1);
            ay += bfhi(u0) + bfhi(u1);
        }
        ax += __shfl_xor(ax, 8);  ay += __shfl_xor(ay, 8);
        ax += __shfl_xor(ax, 16); ay += __shfl_xor(ay, 16);
        ax += __shfl_xor(ax, 32); ay += __shfl_xor(ay, 32);
        if (eg == 0) {
            unsigned us = hs2[(size_t)wv * 64 + chof];    // self-loop term
            float dv = dinv[wv];
            aggS[((size_t)g * N_NODES + wv) * 8 + ch] =
                bfpack((ax + bflo(us)) * dv, (ay + bfhi(us)) * dv);
        }
    }
}

// ------- bias + LayerNorm + ReLU over the sliced agg (wave per node) -------
__global__ __launch_bounds__(256) void k_ln(
    const unsigned* __restrict__ aggS, const float* __restrict__ b,
    const float* __restrict__ gam, const float* __restrict__ be,
    unsigned* __restrict__ out) {
    int wv = blockIdx.x * 4 + (threadIdx.x >> 6);
    int lane = threadIdx.x & 63;
    if (wv >= N_NODES) return;
    int g = lane >> 3, ch = lane & 7;            // channel-pair index == lane
    unsigned u = aggS[((size_t)g * N_NODES + wv) * 8 + ch];
    float t0 = bflo(u) + b[2 * lane];
    float t1 = bfhi(u) + b[2 * lane + 1];
    float ssum = t0 + t1;
#pragma unroll
    for (int o = 32; o; o >>= 1) ssum += __shfl_xor(ssum, o);
    float mu = ssum * (1.0f / 128.0f);
    float d0 = t0 - mu, d1 = t1 - mu;
    float vs = d0 * d0 + d1 * d1;
#pragma unroll
    for (int o = 32; o; o >>= 1) vs += __shfl_xor(vs, o);
    float rstd = rsqrtf(vs * (1.0f / 128.0f) + LN_EPS);
    float y0 = d0 * rstd * gam[2 * lane] + be[2 * lane];
    float y1 = d1 * rstd * gam[2 * lane + 1] + be[2 * lane + 1];
    y0 = y0 > 0.f ? y0 : 0.f;
    y1 = y1 > 0.f ? y1 : 0.f;
    out[(size_t)wv * 64 + lane] = bfpack(y0, y1);
}

extern "C" void kernel_launch(void* const* d_in, const int* in_sizes, int n_in,
                              void* d_out, int out_size, void* d_ws, size_t ws_size,
                              hipStream_t stream) {
    (void)in_sizes; (void)n_in; (void)out_size; (void)ws_size;
    const float* x   = (const float*)d_in[0];
    const int*   ei  = (const int*)d_in[1];
    const float* W1  = (const float*)d_in[2];
    const float* b1  = (const float*)d_in[3];
    const float* g1  = (const float*)d_in[4];
    const float* be1 = (const float*)d_in[5];
    const float* W2  = (const float*)d_in[6];
    const float* b2  = (const float*)d_in[7];
    const float* g2  = (const float*)d_in[8];
    const float* be2 = (const float*)d_in[9];
    const float* Wm1 = (const float*)d_in[10];
    const float* bm1 = (const float*)d_in[11];
    const float* Wm2 = (const float*)d_in[12];
    const float* bm2 = (const float*)d_in[13];
    const int* srcI = ei;
    const int* dstI = ei + N_EDGES;
    float* out = (float*)d_out;

    char* ws = (char*)d_ws;
    size_t off = 0;
    auto alloc = [&](size_t bytes) -> char* {
        char* p = ws + off;
        off += (bytes + 255) & ~(size_t)255;
        return p;
    };
    short* xb      = (short*)alloc((size_t)N_NODES * 128 * 2);  // x in bf16
    short* bufS    = (short*)alloc((size_t)N_NODES * 128 * 2);  // hs1/hs2
    short* bufH    = (short*)alloc((size_t)N_NODES * 128 * 2);  // h1n/h2n
    unsigned* aggS = (unsigned*)alloc((size_t)N_NODES * 64 * 4); // sliced agg
    short* Wt1     = (short*)alloc(128 * 128 * 2);
    short* Wt2     = (short*)alloc(128 * 128 * 2);
    short* Wm1t    = (short*)alloc(256 * 128 * 2);
    int* rowptr    = (int*)alloc((size_t)(N_NODES + 1) * 4);
    int* col       = (int*)alloc((size_t)N_EDGES * 4);
    unsigned* pairs = (unsigned*)alloc((size_t)NBUK * BCAP * 4);
    int* gcur      = (int*)alloc(NBUK * 4);
    int* bstart    = (int*)alloc(NBUK * 4);
    float* dinv    = (float*)alloc((size_t)N_NODES * 4);

    hipMemsetAsync(gcur, 0, NBUK * 4, stream);

    // converts
    k_cvt<<<(N_NODES * 32 + 255) / 256, 256, 0, stream>>>((const f32x4*)x, (unsigned*)xb);
    k_wtall<<<256, 256, 0, stream>>>(W1, W2, Wm1, Wt1, Wt2, Wm1t);

    // bucketed CSR
    k_bin<<<(N_EDGES + BIN_TILE - 1) / BIN_TILE, 256, 0, stream>>>(srcI, dstI, gcur, pairs);
    k_bstart<<<1, 1024, 0, stream>>>(gcur, bstart, rowptr);
    k_csr<<<NBUK, 256, 0, stream>>>(pairs, gcur, bstart, rowptr, dinv, col);

    int gb = (N_NODES + 63) / 64;
    int sb = 8 * ((N_NODES + 31) / 32);   // 8 slices x node-blocks (32 nodes/block)
    int lb = (N_NODES + 3) / 4;
    // layer 1
    k_gemm_mfma<0, 4><<<gb, 256, 0, stream>>>(xb, nullptr, Wt1, dinv, nullptr, bufS,
                                              nullptr, nullptr, nullptr);
    k_sagg<<<sb, 256, 0, stream>>>((unsigned*)bufS, rowptr, col, dinv, aggS);
    k_ln<<<lb, 256, 0, stream>>>(aggS, b1, g1, be1, (unsigned*)bufH);
    // layer 2
    k_gemm_mfma<0, 4><<<gb, 256, 0, stream>>>(bufH, nullptr, Wt2, dinv, nullptr, bufS,
                                              nullptr, nullptr, nullptr);
    k_sagg<<<sb, 256, 0, stream>>>((unsigned*)bufS, rowptr, col, dinv, aggS);
    k_ln<<<lb, 256, 0, stream>>>(aggS, b2, g2, be2, (unsigned*)bufH);
    // fused MLP (hidden GEMM + relu + final 128x2 + bias)
    k_gemm_mfma<1, 8><<<gb, 256, 0, stream>>>(bufH, xb, Wm1t, nullptr, bm1, nullptr,
                                              Wm2, bm2, out);
}

// Round 8
// 350.142 us; speedup vs baseline: 2.6046x; 2.6046x over previous
//
#include <hip/hip_runtime.h>
#include <math.h>

#define N_NODES 100000
#define N_EDGES 1600000
#define LN_EPS 1e-5f
#define NBUK 782          // ceil(100000/128) buckets of 128 nodes
#define BCAP 2560         // bucket capacity (mean 2046, sd ~45; ~11 sigma)
#define BIN_TILE 4096     // edges per k_bin block

using bf16x8 = __attribute__((ext_vector_type(8))) short;
using f32x4  = __attribute__((ext_vector_type(4))) float;
using u32x4  = __attribute__((ext_vector_type(4))) unsigned;

__device__ __forceinline__ unsigned short f2bf(float f) {
    unsigned u = __float_as_uint(f);
    u += 0x7fffu + ((u >> 16) & 1u);            // round-to-nearest-even
    return (unsigned short)(u >> 16);
}
__device__ __forceinline__ float bflo(unsigned u) { return __uint_as_float(u << 16); }
__device__ __forceinline__ float bfhi(unsigned u) { return __uint_as_float(u & 0xffff0000u); }
__device__ __forceinline__ unsigned bfpack(float a, float b) {
    return (unsigned)f2bf(a) | ((unsigned)f2bf(b) << 16);
}

// ---------------- converts ----------------

__global__ void k_cvt(const f32x4* __restrict__ x, unsigned* __restrict__ xb) {
    int i = blockIdx.x * 256 + threadIdx.x;     // 4 floats per thread
    if (i < N_NODES * 32) {
        f32x4 v = __builtin_nontemporal_load(&x[i]);
        xb[2 * i]     = bfpack(v[0], v[1]);
        xb[2 * i + 1] = bfpack(v[2], v[3]);
    }
}

// all three weights fp32 -> transposed bf16 in one launch
__global__ void k_wtall(const float* __restrict__ W1, const float* __restrict__ W2,
                        const float* __restrict__ Wm1, short* __restrict__ Wt1,
                        short* __restrict__ Wt2, short* __restrict__ Wm1t) {
    int i = blockIdx.x * 256 + threadIdx.x;
    if (i < 16384) {
        int k = i >> 7, c = i & 127;
        Wt1[c * 128 + k] = (short)f2bf(W1[i]);
    } else if (i < 32768) {
        int j = i - 16384, k = j >> 7, c = j & 127;
        Wt2[c * 128 + k] = (short)f2bf(W2[j]);
    } else if (i < 65536) {
        int j = i - 32768, k = j >> 7, c = j & 127;
        Wm1t[c * 256 + k] = (short)f2bf(Wm1[j]);
    }
}

// ---------------- bucketed CSR build ----------------
__global__ __launch_bounds__(256) void k_bin(
    const int* __restrict__ src, const int* __restrict__ dst,
    int* __restrict__ gcur, unsigned* __restrict__ pairs) {
    __shared__ int bcnt[NBUK];
    __shared__ int bbase[NBUK];
    int t = threadIdx.x;
    for (int i = t; i < NBUK; i += 256) bcnt[i] = 0;
    __syncthreads();
    int e0 = blockIdx.x * BIN_TILE;
    int e1 = e0 + BIN_TILE; if (e1 > N_EDGES) e1 = N_EDGES;
    for (int e = e0 + t; e < e1; e += 256) {
        int d = __builtin_nontemporal_load(&dst[e]);
        atomicAdd(&bcnt[d >> 7], 1);
    }
    __syncthreads();
    for (int i = t; i < NBUK; i += 256) {
        int c = bcnt[i];
        bbase[i] = (c > 0) ? atomicAdd(&gcur[i], c) : 0;
        bcnt[i] = 0;
    }
    __syncthreads();
    for (int e = e0 + t; e < e1; e += 256) {
        int d = __builtin_nontemporal_load(&dst[e]);
        int s = __builtin_nontemporal_load(&src[e]);
        int b = d >> 7;
        int idx = bbase[b] + atomicAdd(&bcnt[b], 1);
        if (idx < BCAP)
            pairs[(size_t)b * BCAP + idx] = ((unsigned)(d & 127) << 25) | (unsigned)s;
    }
}

__global__ void k_bstart(const int* __restrict__ gcur, int* __restrict__ bstart,
                         int* __restrict__ rowptr) {
    __shared__ int s[1024];
    int tid = threadIdx.x;
    int v = (tid < NBUK) ? gcur[tid] : 0;
    s[tid] = v;
    __syncthreads();
    for (int o = 1; o < 1024; o <<= 1) {
        int tv = (tid >= o) ? s[tid - o] : 0;
        __syncthreads();
        s[tid] += tv;
        __syncthreads();
    }
    if (tid < NBUK) bstart[tid] = s[tid] - v;
    if (tid == 0) rowptr[N_NODES] = N_EDGES;
}

__global__ __launch_bounds__(256) void k_csr(
    const unsigned* __restrict__ pairs, const int* __restrict__ gcur,
    const int* __restrict__ bstart, int* __restrict__ rowptr,
    float* __restrict__ dinv, int* __restrict__ col) {
    int b = blockIdx.x;
    int t = threadIdx.x;
    int lo = b << 7;
    int nloc = N_NODES - lo; if (nloc > 128) nloc = 128;
    int size = gcur[b]; if (size > BCAP) size = BCAP;
    int base = bstart[b];
    __shared__ int lcnt[128], lofs[128], lcur[128];
    if (t < 128) lcnt[t] = 0;
    __syncthreads();
    const unsigned* bp = pairs + (size_t)b * BCAP;
    for (int i = t; i < size; i += 256) atomicAdd(&lcnt[bp[i] >> 25], 1);
    __syncthreads();
    if (t < 128) lofs[t] = lcnt[t];
    __syncthreads();
    for (int o = 1; o < 128; o <<= 1) {
        int v = 0;
        if (t < 128 && t >= o) v = lofs[t - o];
        __syncthreads();
        if (t < 128) lofs[t] += v;
        __syncthreads();
    }
    if (t < 128) {
        int ex = lofs[t] - lcnt[t];               // exclusive
        if (t < nloc) {
            rowptr[lo + t] = base + ex;
            dinv[lo + t] = rsqrtf((float)(lcnt[t] + 1));
        }
        lcur[t] = ex;
    }
    __syncthreads();
    for (int i = t; i < size; i += 256) {
        unsigned w = bp[i];
        int pos = atomicAdd(&lcur[w >> 25], 1);
        col[base + pos] = (int)(w & 0x1FFFFFFu);
    }
}

// ------------- bf16 MFMA GEMM  C[N,128] = A[N,K] @ W[K,128] -------------
// MODE 0: epilogue *dinv[row], write bf16 C.
// MODE 1: A=concat(A0,A1) (K=256); epilogue relu(.+bias) @ Wm2 + bm2 -> out[N,2]
template <int MODE, int KSTEPS>
__global__ __launch_bounds__(256) void k_gemm_mfma(
    const short* __restrict__ A0, const short* __restrict__ A1,
    const short* __restrict__ Wt, const float* __restrict__ dinv,
    const float* __restrict__ bias, short* __restrict__ C,
    const float* __restrict__ Wm2, const float* __restrict__ bm2,
    float* __restrict__ out) {
    constexpr int K = KSTEPS * 32;
    int t = threadIdx.x;
    int wave = t >> 6, lane = t & 63;
    int quad = lane >> 4, fr = lane & 15;
    int row0 = blockIdx.x * 64 + wave * 16;
    int arow = row0 + fr;
    if (arow >= N_NODES) arow = N_NODES - 1;

    f32x4 acc[8];
#pragma unroll
    for (int n = 0; n < 8; ++n) acc[n] = (f32x4){0.f, 0.f, 0.f, 0.f};

#pragma unroll
    for (int ks = 0; ks < KSTEPS; ++ks) {
        int kof = ks * 32 + quad * 8;
        const short* Asrc = A0;
        int kk = kof;
        if (MODE == 1 && kof >= 128) { Asrc = A1; kk = kof - 128; }
        bf16x8 a = *(const bf16x8*)(Asrc + (size_t)arow * 128 + kk);
#pragma unroll
        for (int n = 0; n < 8; ++n) {
            bf16x8 b = *(const bf16x8*)(Wt + (size_t)(n * 16 + fr) * K + kof);
            acc[n] = __builtin_amdgcn_mfma_f32_16x16x32_bf16(a, b, acc[n], 0, 0, 0);
        }
    }

    int r0 = row0 + quad * 4;
    if (MODE == 0) {
#pragma unroll
        for (int j = 0; j < 4; ++j) {
            int r = r0 + j;
            if (r < N_NODES) {
                float s = dinv[r];
#pragma unroll
                for (int n = 0; n < 8; ++n)
                    C[(size_t)r * 128 + n * 16 + fr] = (short)f2bf(acc[n][j] * s);
            }
        }
    } else {
        // fused MLP tail: y = relu(acc + bm1); out = y @ Wm2 + bm2
        float pr0[4] = {0.f, 0.f, 0.f, 0.f};
        float pr1[4] = {0.f, 0.f, 0.f, 0.f};
#pragma unroll
        for (int n = 0; n < 8; ++n) {
            int c = n * 16 + fr;
            float bsn = bias[c];
            float2 w = ((const float2*)Wm2)[c];
#pragma unroll
            for (int j = 0; j < 4; ++j) {
                float y = acc[n][j] + bsn;
                y = y > 0.f ? y : 0.f;
                pr0[j] = fmaf(y, w.x, pr0[j]);
                pr1[j] = fmaf(y, w.y, pr1[j]);
            }
        }
#pragma unroll
        for (int o = 1; o < 16; o <<= 1) {
#pragma unroll
            for (int j = 0; j < 4; ++j) {
                pr0[j] += __shfl_xor(pr0[j], o);
                pr1[j] += __shfl_xor(pr1[j], o);
            }
        }
        if (fr == 0) {
            float c0 = bm2[0], c1 = bm2[1];
#pragma unroll
            for (int j = 0; j < 4; ++j) {
                int r = r0 + j;
                if (r < N_NODES) {
                    out[(size_t)r * 2 + 0] = pr0[j] + c0;
                    out[(size_t)r * 2 + 1] = pr1[j] + c1;
                }
            }
        }
    }
}

// ------- fused pull-aggregate + bias + LayerNorm + ReLU (wave per node) -------
// Layout: 16 lanes per edge-row (uint4 each = 256B row), 4 edge-groups per wave.
// 2 loads in flight -> 8 edges; 1KB per load instruction.
__global__ __launch_bounds__(256) void k_agg(
    const unsigned* __restrict__ hs2, const int* __restrict__ rowptr,
    const int* __restrict__ col, const float* __restrict__ dinv,
    const float* __restrict__ b, const float* __restrict__ g,
    const float* __restrict__ be, unsigned* __restrict__ out) {
    int wv = blockIdx.x * 4 + (threadIdx.x >> 6);
    int lane = threadIdx.x & 63;
    if (wv >= N_NODES) return;
    const u32x4* hs4 = (const u32x4*)hs2;
    int e4 = lane >> 4, ch16 = lane & 15;       // edge-group, row-quarter
    int p0 = rowptr[wv], p1 = rowptr[wv + 1];
    int ne = p1 - p0;
    float a[8];
#pragma unroll
    for (int q = 0; q < 8; ++q) a[q] = 0.f;
    for (int base = 0; base < ne; base += 64) {
        int rem = ne - base;
        if (rem > 64) rem = 64;
        int myc = (lane < rem) ? col[p0 + base + lane] : -1;
        for (int j = 0; j < rem; j += 8) {
            int sa = __shfl(myc, j + e4);
            int sb = __shfl(myc, j + 4 + e4);
            u32x4 ua = (sa >= 0) ? hs4[(size_t)sa * 16 + ch16] : (u32x4){0, 0, 0, 0};
            u32x4 ub = (sb >= 0) ? hs4[(size_t)sb * 16 + ch16] : (u32x4){0, 0, 0, 0};
#pragma unroll
            for (int q = 0; q < 4; ++q) {
                a[2 * q]     += bflo(ua[q]) + bflo(ub[q]);
                a[2 * q + 1] += bfhi(ua[q]) + bfhi(ub[q]);
            }
        }
    }
    // combine the 4 edge-groups: lanes differing only in bits 4-5
#pragma unroll
    for (int q = 0; q < 8; ++q) {
        a[q] += __shfl_xor(a[q], 16);
        a[q] += __shfl_xor(a[q], 32);
    }
    // epilogue (all 4 groups compute identically; group 0 writes)
    u32x4 us = hs4[(size_t)wv * 16 + ch16];     // self-loop term
    float dv = dinv[wv];
    const float2* b2 = (const float2*)b;
    const float2* g2 = (const float2*)g;
    const float2* be2 = (const float2*)be;
    float tv[8];
#pragma unroll
    for (int q = 0; q < 4; ++q) {
        float2 bb = b2[ch16 * 4 + q];
        tv[2 * q]     = (a[2 * q] + bflo(us[q])) * dv + bb.x;
        tv[2 * q + 1] = (a[2 * q + 1] + bfhi(us[q])) * dv + bb.y;
    }
    float ssum = 0.f;
#pragma unroll
    for (int q = 0; q < 8; ++q) ssum += tv[q];
#pragma unroll
    for (int o = 1; o < 16; o <<= 1) ssum += __shfl_xor(ssum, o);
    float mu = ssum * (1.0f / 128.0f);
    float vs = 0.f;
#pragma unroll
    for (int q = 0; q < 8; ++q) { float d = tv[q] - mu; vs += d * d; }
#pragma unroll
    for (int o = 1; o < 16; o <<= 1) vs += __shfl_xor(vs, o);
    float rstd = rsqrtf(vs * (1.0f / 128.0f) + LN_EPS);
    if (e4 == 0) {
        u32x4 w;
#pragma unroll
        for (int q = 0; q < 4; ++q) {
            float2 gg = g2[ch16 * 4 + q];
            float2 bb = be2[ch16 * 4 + q];
            float y0 = (tv[2 * q] - mu) * rstd * gg.x + bb.x;
            float y1 = (tv[2 * q + 1] - mu) * rstd * gg.y + bb.y;
            y0 = y0 > 0.f ? y0 : 0.f;
            y1 = y1 > 0.f ? y1 : 0.f;
            w[q] = bfpack(y0, y1);
        }
        ((u32x4*)out)[(size_t)wv * 16 + ch16] = w;
    }
}

extern "C" void kernel_launch(void* const* d_in, const int* in_sizes, int n_in,
                              void* d_out, int out_size, void* d_ws, size_t ws_size,
                              hipStream_t stream) {
    (void)in_sizes; (void)n_in; (void)out_size; (void)ws_size;
    const float* x   = (const float*)d_in[0];
    const int*   ei  = (const int*)d_in[1];
    const float* W1  = (const float*)d_in[2];
    const float* b1  = (const float*)d_in[3];
    const float* g1  = (const float*)d_in[4];
    const float* be1 = (const float*)d_in[5];
    const float* W2  = (const float*)d_in[6];
    const float* b2  = (const float*)d_in[7];
    const float* g2  = (const float*)d_in[8];
    const float* be2 = (const float*)d_in[9];
    const float* Wm1 = (const float*)d_in[10];
    const float* bm1 = (const float*)d_in[11];
    const float* Wm2 = (const float*)d_in[12];
    const float* bm2 = (const float*)d_in[13];
    const int* srcI = ei;
    const int* dstI = ei + N_EDGES;
    float* out = (float*)d_out;

    char* ws = (char*)d_ws;
    size_t off = 0;
    auto alloc = [&](size_t bytes) -> char* {
        char* p = ws + off;
        off += (bytes + 255) & ~(size_t)255;
        return p;
    };
    short* xb      = (short*)alloc((size_t)N_NODES * 128 * 2);  // x in bf16
    short* bufS    = (short*)alloc((size_t)N_NODES * 128 * 2);  // hs1/hs2
    short* bufH    = (short*)alloc((size_t)N_NODES * 128 * 2);  // h1n/h2n
    short* Wt1     = (short*)alloc(128 * 128 * 2);
    short* Wt2     = (short*)alloc(128 * 128 * 2);
    short* Wm1t    = (short*)alloc(256 * 128 * 2);
    int* rowptr    = (int*)alloc((size_t)(N_NODES + 1) * 4);
    int* col       = (int*)alloc((size_t)N_EDGES * 4);
    unsigned* pairs = (unsigned*)alloc((size_t)NBUK * BCAP * 4);
    int* gcur      = (int*)alloc(NBUK * 4);
    int* bstart    = (int*)alloc(NBUK * 4);
    float* dinv    = (float*)alloc((size_t)N_NODES * 4);

    hipMemsetAsync(gcur, 0, NBUK * 4, stream);

    // converts
    k_cvt<<<(N_NODES * 32 + 255) / 256, 256, 0, stream>>>((const f32x4*)x, (unsigned*)xb);
    k_wtall<<<256, 256, 0, stream>>>(W1, W2, Wm1, Wt1, Wt2, Wm1t);

    // bucketed CSR
    k_bin<<<(N_EDGES + BIN_TILE - 1) / BIN_TILE, 256, 0, stream>>>(srcI, dstI, gcur, pairs);
    k_bstart<<<1, 1024, 0, stream>>>(gcur, bstart, rowptr);
    k_csr<<<NBUK, 256, 0, stream>>>(pairs, gcur, bstart, rowptr, dinv, col);

    int gb = (N_NODES + 63) / 64;
    int ab = (N_NODES + 3) / 4;
    // layer 1
    k_gemm_mfma<0, 4><<<gb, 256, 0, stream>>>(xb, nullptr, Wt1, dinv, nullptr, bufS,
                                              nullptr, nullptr, nullptr);
    k_agg<<<ab, 256, 0, stream>>>((unsigned*)bufS, rowptr, col, dinv, b1, g1, be1, (unsigned*)bufH);
    // layer 2
    k_gemm_mfma<0, 4><<<gb, 256, 0, stream>>>(bufH, nullptr, Wt2, dinv, nullptr, bufS,
                                              nullptr, nullptr, nullptr);
    k_agg<<<ab, 256, 0, stream>>>((unsigned*)bufS, rowptr, col, dinv, b2, g2, be2, (unsigned*)bufH);
    // fused MLP (hidden GEMM + relu + final 128x2 + bias)
    k_gemm_mfma<1, 8><<<gb, 256, 0, stream>>>(bufH, xb, Wm1t, nullptr, bm1, nullptr,
                                              Wm2, bm2, out);
}